// Round 15
// baseline (163.566 us; speedup 1.0000x reference)
//
#include <hip/hip_runtime.h>

#define NPTS   16384
#define NDIM   64
#define NBATCH 8
#define TB     1024
#define VPT    16      // NPTS / TB
#define NB     8192    // histogram bins
#define BPT    8       // NB / TB
#define EPSF   0.1f
#define MINS   5
#define NCMAX  512
#define BIGI   0x3fffffff

typedef short short8 __attribute__((ext_vector_type(8)));
typedef float f32x4  __attribute__((ext_vector_type(4)));

// LDS swizzles: spread per-thread-contiguous accesses across banks (bijective XOR)
__device__ __forceinline__ int phys(int i)  { return i ^ ((i >> 5) & 15); }          // float array
__device__ __forceinline__ int lphys(int i) { return i ^ (((i >> 6) & 31) << 1); }   // short array

__device__ __forceinline__ int binof(float x, float mn, float inv) {
  float fb = (x - mn) * inv;
  int b = (int)fb;
  if (fb < 0.f) b = 0;
  if (b > NB - 1) b = NB - 1;
  return b;
}

// monotone float<->uint order-preserving map (for atomicMin/Max)
__device__ __forceinline__ unsigned flipf(float x) {
  unsigned u = __float_as_uint(x);
  return (u & 0x80000000u) ? ~u : (u | 0x80000000u);
}
__device__ __forceinline__ float unflipf(unsigned y) {
  return __uint_as_float((y & 0x80000000u) ? (y & 0x7FFFFFFFu) : ~y);
}

// ------ transpose (B,N,D) -> (B,D,N) + per-(b,d) min/max reduction ------
__global__ void ktrans(const float* __restrict__ f, float* __restrict__ xt,
                       unsigned* __restrict__ mng, unsigned* __restrict__ mxg) {
  __shared__ float tile[64][65];
  __shared__ unsigned smn[64], smx[64];
  const int tid = threadIdx.x;
  int blk = blockIdx.x;
  int b   = blk >> 8;
  int n0  = (blk & 255) << 6;
  if (tid < 64) { smn[tid] = 0xFFFFFFFFu; smx[tid] = 0u; }
  float lmn = INFINITY, lmx = -INFINITY;
  for (int i = tid; i < 64 * 64; i += 256) {         // d = tid&63 fixed per thread
    int n = i >> 6, d = i & 63;
    float t = f[((size_t)b * NPTS + n0 + n) * NDIM + d];
    tile[n][d] = t;
    lmn = fminf(lmn, t); lmx = fmaxf(lmx, t);
  }
  __syncthreads();                                   // tile + smn/smx init visible
  atomicMin(&smn[tid & 63], flipf(lmn));
  atomicMax(&smx[tid & 63], flipf(lmx));
  __syncthreads();
  for (int i = tid; i < 64 * 64; i += 256) {
    int d = i >> 6, n = i & 63;
    xt[((size_t)b * NDIM + d) * NPTS + n0 + n] = tile[n][d];
  }
  if (tid < 64)       atomicMin(&mng[b * 64 + tid], smn[tid]);
  else if (tid < 128) atomicMax(&mxg[b * 64 + (tid - 64)], smx[tid - 64]);
}

// forward-scan monoid: (has core, first core val, last core val, #internal starts)
struct FS { int h; float f; float l; int c; };
__device__ __forceinline__ FS fsid() { FS r; r.h = 0; r.f = 0.f; r.l = 0.f; r.c = 0; return r; }
__device__ __forceinline__ FS fscomb(FS a, FS b) {
  FS r;
  r.h = a.h | b.h;
  r.f = a.h ? a.f : b.f;
  r.l = b.h ? b.l : a.l;
  int gap = (a.h && b.h && ((b.f - a.l) > EPSF)) ? 1 : 0;
  r.c = a.c + b.c + gap;
  return r;
}

// ---------------- per-(b,d) exact 1-D DBSCAN (9-barrier schedule) ----------------
__global__ void __launch_bounds__(TB) kdbscan(const float* __restrict__ xt,
                                              const unsigned* __restrict__ mng,
                                              const unsigned* __restrict__ mxg,
                                              short* __restrict__ labels,
                                              int* __restrict__ nclg) {
  const int tid  = threadIdx.x;
  const int lane = tid & 63;
  const int wid  = tid >> 6;
  const int bd   = blockIdx.x;
  const float* __restrict__ x = xt + (size_t)bd * NPTS;

  __shared__ float xs[NPTS];            // 64 KB (phys-swizzled)
  __shared__ unsigned int hist[NB];     // 32 KB : counts -> scatter counters -> lab[]
  __shared__ unsigned int offs[NB + 1]; // 32 KB : bin STARTS (read-only after phase 3)
  __shared__ unsigned int wsum[16];
  __shared__ int   sh[16];  __shared__ float sf[16], sl[16]; __shared__ int sc[16];
  __shared__ int   wri[16]; __shared__ float wrv[16];
  short* lab = (short*)hist;            // lphys-swizzled labels per sorted position

  // ---- 1. precomputed min/max; overlap hist init with v loads ----
  float mn = unflipf(mng[bd]);
  float mx = unflipf(mxg[bd]);
  float range = mx - mn;
  float inv = (range > 0.f) ? ((float)NB / range) : 0.f;
  for (int i = tid; i < NB; i += TB) hist[i] = 0u;
  float v[VPT];
  #pragma unroll
  for (int s = 0; s < VPT; ++s) v[s] = x[tid + s * TB];
  __syncthreads();                                   // B1: hist zeroed

  // ---- 2. histogram ----
  #pragma unroll
  for (int s = 0; s < VPT; ++s) atomicAdd(&hist[binof(v[s], mn, inv)], 1u);
  __syncthreads();                                   // B2

  // ---- 3. exclusive prefix sum -> offs = bin starts; offs[NB] = NPTS ----
  unsigned int loc[BPT];
  unsigned int run = 0;
  const int bbase = tid * BPT;
  #pragma unroll
  for (int j = 0; j < BPT; ++j) { loc[j] = run; run += hist[bbase + j]; }
  unsigned int incl = run;
  for (int d = 1; d < 64; d <<= 1) {
    unsigned int u = __shfl_up(incl, d);
    if (lane >= d) incl += u;
  }
  unsigned int exc = __shfl_up(incl, 1);
  if (lane == 0) exc = 0u;
  if (lane == 63) wsum[wid] = incl;
  __syncthreads();                                   // B3
  unsigned int wb = 0;
  for (int w = 0; w < wid; ++w) wb += wsum[w];
  unsigned int tb0 = wb + exc;
  #pragma unroll
  for (int j = 0; j < BPT; ++j) offs[bbase + j] = tb0 + loc[j];
  if (tid == TB - 1) offs[NB] = NPTS;
  __syncthreads();                                   // B4

  // ---- 4. scatter (atomicSub on hist -> reverse fill; offs untouched) ----
  int pos[VPT];
  #pragma unroll
  for (int s = 0; s < VPT; ++s) {
    int b = binof(v[s], mn, inv);
    unsigned old = atomicSub(&hist[b], 1u);
    int p = (int)(offs[b] + old - 1u);
    pos[s] = p | (b << 14);
    xs[phys(p)] = v[s];
  }
  __syncthreads();                                   // B5: hist all-zero (dead)

  // ---- 5. parallel rank within bin -> exact sorted position (stable via slot) ----
  int tgt[VPT];
  #pragma unroll
  for (int s = 0; s < VPT; ++s) {
    int b  = pos[s] >> 14;
    int pp = pos[s] & 0x3FFF;
    int s0 = (int)offs[b];
    int e0 = (int)offs[b + 1];
    float vv = v[s];
    int r = 0;
    for (int j = s0; j < e0; ++j) {
      float xj = xs[phys(j)];
      r += (xj < vv || (xj == vv && j < pp)) ? 1 : 0;
    }
    tgt[s] = s0 + r;
  }
  __syncthreads();                                   // B6; pos[] dead

  // ---- 6. write sorted order from registers ----
  #pragma unroll
  for (int s = 0; s < VPT; ++s) xs[phys(tgt[s])] = v[s];
  __syncthreads();                                   // B7: xs sorted; v[] dead

  // ---- 7. window read + core flags + FS seed + backward seed ----
  const int p0 = tid * VPT;
  float w[VPT + 8];
  #pragma unroll
  for (int k = 0; k < VPT + 8; ++k) {
    int i = p0 - 4 + k;
    w[k] = (i < 0) ? -INFINITY : ((i >= NPTS) ? INFINITY : xs[phys(i)]);
  }
  unsigned int coremask = 0u;
  FS ch = fsid();
  int fi = BIGI; float fv = 0.f;
  #pragma unroll
  for (int s = 0; s < VPT; ++s) {
    float xi = w[s + 4];
    float lo = xi - EPSF, hi = xi + EPSF;
    bool core = false;
    #pragma unroll
    for (int t = 0; t < MINS; ++t)
      core |= (w[s + 4 - t] >= lo) && (w[s + 8 - t] <= hi);
    if (core) {
      coremask |= (1u << s);
      if (!ch.h) { ch.h = 1; ch.f = xi; }
      else if ((xi - ch.l) > EPSF) ++ch.c;
      ch.l = xi;
      if (fi == BIGI) { fi = p0 + s; fv = xi; }
    }
  }

  // ---- 8+9 fused: forward FS scan AND backward next-core scan, one barrier ----
  FS cur = ch;
  for (int d = 1; d < 64; d <<= 1) {
    FS u;
    u.h = __shfl_up(cur.h, d);
    u.f = __shfl_up(cur.f, d);
    u.l = __shfl_up(cur.l, d);
    u.c = __shfl_up(cur.c, d);
    FS cmb = fscomb(u, cur);
    if (lane >= d) cur = cmb;
  }
  FS exs;
  exs.h = __shfl_up(cur.h, 1);
  exs.f = __shfl_up(cur.f, 1);
  exs.l = __shfl_up(cur.l, 1);
  exs.c = __shfl_up(cur.c, 1);
  if (lane == 0) exs = fsid();

  int ri = fi; float rv = fv;
  for (int d = 1; d < 64; d <<= 1) {
    int ui = __shfl_down(ri, d); float uv = __shfl_down(rv, d);
    if (lane < 64 - d && ui < ri) { ri = ui; rv = uv; }
  }
  int Ri = __shfl_down(ri, 1); float Rv = __shfl_down(rv, 1);
  if (lane == 63) Ri = BIGI;

  if (lane == 63) { sh[wid] = cur.h; sf[wid] = cur.f; sl[wid] = cur.l; sc[wid] = cur.c; }
  if (lane == 0)  { wri[wid] = ri;  wrv[wid] = rv; }
  __syncthreads();                                   // B8 (single barrier for both scans)

  FS pre = fsid();
  for (int w2 = 0; w2 < wid; ++w2) {
    FS t; t.h = sh[w2]; t.f = sf[w2]; t.l = sl[w2]; t.c = sc[w2];
    pre = fscomb(pre, t);
  }
  FS sp = fscomb(pre, exs);
  for (int w2 = wid + 1; w2 < 16; ++w2)
    if (wri[w2] < Ri) { Ri = wri[w2]; Rv = wrv[w2]; }

  // ---- 10. single forward label pass (core + border inline) ----
  float P  = sp.h ? sp.l : -INFINITY;       // last core value so far
  int starts = sp.h ? (sp.c + 1) : 0;       // starts-1 = label of P
  #pragma unroll
  for (int s = 0; s < VPT; ++s) {
    int i = p0 + s;
    float xi = w[s + 4];
    short lb;
    if ((coremask >> s) & 1u) {
      if ((xi - P) > EPSF) ++starts;
      P = xi;
      lb = (short)(starts - 1);
    } else {
      float dl = xi - P;                    // +inf when no left core
      unsigned hb = coremask >> (s + 1);    // later cores within this thread
      float Rv2; bool has;
      if (hb) { int j = s + 1 + __builtin_ctz(hb); Rv2 = w[4 + j]; has = true; }
      else    { Rv2 = Rv; has = (Ri < NPTS); }
      float dr = has ? (Rv2 - xi) : INFINITY;
      lb = -1;
      if (fminf(dl, dr) <= EPSF)
        lb = (short)((dl <= dr) ? (starts - 1)
                                : (starts - 1 + (((Rv2 - P) > EPSF) ? 1 : 0)));
    }
    lab[lphys(i)] = lb;
  }
  if (tid == TB - 1) nclg[bd] = starts;
  __syncthreads();                                   // B9: labels visible

  // ---- 11. unsort via tgt; coalesced (b,d,n) label writes ----
  #pragma unroll
  for (int s = 0; s < VPT; ++s)
    labels[(size_t)bd * NPTS + tid + s * TB] = lab[lphys(tgt[s])];
}

// ------- fused zero+scatter with in-block colmap build; vectorized label reads -------
__global__ void __launch_bounds__(TB) kout(const short* __restrict__ labels,
                                           const int* __restrict__ ncl,
                                           float* __restrict__ out) {
  const int tid  = threadIdx.x;
  const int lane = tid & 63;
  const int wid  = tid >> 6;
  const int b    = blockIdx.x >> 5;
  const int n0   = (blockIdx.x & 31) * 512 + wid * 32;

  __shared__ int cmLDS[NCMAX];
  for (int k = tid; k < NCMAX; k += TB) cmLDS[k] = -1;
  __syncthreads();
  if (tid < 64) {
    int vcnt = ncl[b * 64 + tid];
    int incl = vcnt;
    for (int d = 1; d < 64; d <<= 1) {
      int u = __shfl_up(incl, d);
      if (tid >= d) incl += u;
    }
    int off = incl - vcnt;               // exclusive prefix over dims
    for (int k = 0; k < vcnt; ++k) {
      int col = off + k;
      if (col < NCMAX) cmLDS[col] = tid | (k << 8);
    }
  }
  __syncthreads();

  int dk[8], kk[8];
  #pragma unroll
  for (int k = 0; k < 8; ++k) {
    int col = (k < 4) ? (lane * 4 + k) : (256 + lane * 4 + (k - 4));
    int m = cmLDS[col];
    dk[k] = (m >= 0) ? (m & 255) : 0;
    kk[k] = (m >= 0) ? (m >> 8) : 0x7FFF;   // sentinel never matches a label
  }
  const short* lb_b = labels + (size_t)b * NDIM * NPTS;

  #pragma unroll
  for (int rc = 0; rc < 4; ++rc) {
    short8 L[8];
    #pragma unroll
    for (int k = 0; k < 8; ++k)
      L[k] = *(const short8*)(lb_b + (size_t)dk[k] * NPTS + n0 + rc * 8);
    #pragma unroll
    for (int r2 = 0; r2 < 8; ++r2) {
      int n = n0 + rc * 8 + r2;
      float o[8];
      #pragma unroll
      for (int k = 0; k < 8; ++k)
        o[k] = (L[k][r2] == (short)kk[k]) ? 1.0f : 0.0f;
      f32x4* op = (f32x4*)(out + ((size_t)b * NPTS + n) * NCMAX);
      f32x4 lo4 = { o[0], o[1], o[2], o[3] };
      f32x4 hi4 = { o[4], o[5], o[6], o[7] };
      __builtin_nontemporal_store(lo4, &op[lane]);
      __builtin_nontemporal_store(hi4, &op[64 + lane]);
    }
  }
}

extern "C" void kernel_launch(void* const* d_in, const int* in_sizes, int n_in,
                              void* d_out, int out_size, void* d_ws, size_t ws_size,
                              hipStream_t stream) {
  const float* feat = (const float*)d_in[0];
  float* out = (float*)d_out;

  char* ws = (char*)d_ws;
  size_t xt_b   = (size_t)NBATCH * NPTS * NDIM * 4;   // 32 MB
  size_t lbl_b  = (size_t)NBATCH * NPTS * NDIM * 2;   // 16 MB
  float* xt     = (float*)ws;
  short* labels = (short*)(ws + xt_b);
  int*   ncl    = (int*)(ws + xt_b + lbl_b);          // 2 KB
  unsigned* mng = (unsigned*)(ncl + NBATCH * NDIM);   // 2 KB
  unsigned* mxg = mng + NBATCH * NDIM;                // 2 KB

  hipMemsetAsync(mng, 0xFF, NBATCH * NDIM * sizeof(unsigned), stream);
  hipMemsetAsync(mxg, 0x00, NBATCH * NDIM * sizeof(unsigned), stream);
  ktrans  <<<NBATCH * (NPTS / 64), 256, 0, stream>>>(feat, xt, mng, mxg);
  kdbscan <<<NBATCH * NDIM, TB, 0, stream>>>(xt, mng, mxg, labels, ncl);
  kout    <<<NBATCH * 32, TB, 0, stream>>>(labels, ncl, out);
}

// Round 16
// 149.849 us; speedup vs baseline: 1.0915x; 1.0915x over previous
//
#include <hip/hip_runtime.h>

#define NPTS   16384
#define NDIM   64
#define NBATCH 8
#define TB     1024
#define VPT    16      // NPTS / TB
#define NB     8192    // histogram bins
#define BPT    8       // NB / TB
#define EPSF   0.1f
#define MINS   5
#define NCMAX  512
#define BIGI   0x3fffffff

typedef short short8 __attribute__((ext_vector_type(8)));
typedef float f32x4  __attribute__((ext_vector_type(4)));

// LDS swizzles: spread per-thread-contiguous accesses across banks (bijective XOR)
__device__ __forceinline__ int phys(int i)  { return i ^ ((i >> 5) & 15); }          // float array
__device__ __forceinline__ int lphys(int i) { return i ^ (((i >> 6) & 31) << 1); }   // short array

__device__ __forceinline__ int binof(float x, float mn, float inv) {
  float fb = (x - mn) * inv;
  int b = (int)fb;
  if (fb < 0.f) b = 0;
  if (b > NB - 1) b = NB - 1;
  return b;
}

// ---------------- transpose (B,N,D) -> (B,D,N) ----------------
__global__ void ktrans(const float* __restrict__ f, float* __restrict__ xt) {
  __shared__ float tile[64][65];
  int blk = blockIdx.x;
  int b   = blk >> 8;
  int n0  = (blk & 255) << 6;
  for (int i = threadIdx.x; i < 64 * 64; i += 256) {
    int n = i >> 6, d = i & 63;
    tile[n][d] = f[((size_t)b * NPTS + n0 + n) * NDIM + d];
  }
  __syncthreads();
  for (int i = threadIdx.x; i < 64 * 64; i += 256) {
    int d = i >> 6, n = i & 63;
    xt[((size_t)b * NDIM + d) * NPTS + n0 + n] = tile[n][d];
  }
}

// forward-scan monoid: (has core, first core val, last core val, #internal starts)
struct FS { int h; float f; float l; int c; };
__device__ __forceinline__ FS fsid() { FS r; r.h = 0; r.f = 0.f; r.l = 0.f; r.c = 0; return r; }
__device__ __forceinline__ FS fscomb(FS a, FS b) {
  FS r;
  r.h = a.h | b.h;
  r.f = a.h ? a.f : b.f;
  r.l = b.h ? b.l : a.l;
  int gap = (a.h && b.h && ((b.f - a.l) > EPSF)) ? 1 : 0;
  r.c = a.c + b.c + gap;
  return r;
}

// ---------------- per-(b,d) exact 1-D DBSCAN (8-barrier schedule) ----------------
__global__ void __launch_bounds__(TB) kdbscan(const float* __restrict__ xt,
                                              short* __restrict__ labels,
                                              int* __restrict__ nclg) {
  const int tid  = threadIdx.x;
  const int lane = tid & 63;
  const int wid  = tid >> 6;
  const int bd   = blockIdx.x;
  const float* __restrict__ x = xt + (size_t)bd * NPTS;

  __shared__ float xs[NPTS];            // 64 KB (phys-swizzled)
  __shared__ unsigned int hist[NB];     // 32 KB : counts -> scatter counters -> lab[]
  __shared__ unsigned int offs[NB + 1]; // 32 KB : bin STARTS (read-only after phase 3)
  __shared__ float wmn[16], wmx[16];
  __shared__ unsigned int wsum[16];
  __shared__ int   sh[16];  __shared__ float sf[16], sl[16]; __shared__ int sc[16];
  __shared__ int   wri[16]; __shared__ float wrv[16];
  short* lab = (short*)hist;            // lphys-swizzled labels per sorted position

  // ---- 1. hist init overlapped with load + min/max ----
  for (int i = tid; i < NB; i += TB) hist[i] = 0u;
  float v[VPT];
  float mn = INFINITY, mx = -INFINITY;
  #pragma unroll
  for (int s = 0; s < VPT; ++s) {
    v[s] = x[tid + s * TB];
    mn = fminf(mn, v[s]); mx = fmaxf(mx, v[s]);
  }
  for (int d = 1; d < 64; d <<= 1) {
    mn = fminf(mn, __shfl_xor(mn, d));
    mx = fmaxf(mx, __shfl_xor(mx, d));
  }
  if (lane == 0) { wmn[wid] = mn; wmx[wid] = mx; }
  __syncthreads();                                   // B1: hist zeroed + wmn/wmx visible
  mn = wmn[0]; mx = wmx[0];
  for (int w = 1; w < 16; ++w) { mn = fminf(mn, wmn[w]); mx = fmaxf(mx, wmx[w]); }
  float range = mx - mn;
  float inv = (range > 0.f) ? ((float)NB / range) : 0.f;

  // ---- 2. histogram ----
  #pragma unroll
  for (int s = 0; s < VPT; ++s) atomicAdd(&hist[binof(v[s], mn, inv)], 1u);
  __syncthreads();                                   // B2

  // ---- 3. exclusive prefix sum -> offs = bin starts; offs[NB] = NPTS ----
  unsigned int loc[BPT];
  unsigned int run = 0;
  const int bbase = tid * BPT;
  #pragma unroll
  for (int j = 0; j < BPT; ++j) { loc[j] = run; run += hist[bbase + j]; }
  unsigned int incl = run;
  for (int d = 1; d < 64; d <<= 1) {
    unsigned int u = __shfl_up(incl, d);
    if (lane >= d) incl += u;
  }
  unsigned int exc = __shfl_up(incl, 1);
  if (lane == 0) exc = 0u;
  if (lane == 63) wsum[wid] = incl;
  __syncthreads();                                   // B3
  unsigned int wb = 0;
  for (int w = 0; w < wid; ++w) wb += wsum[w];
  unsigned int tb0 = wb + exc;
  #pragma unroll
  for (int j = 0; j < BPT; ++j) offs[bbase + j] = tb0 + loc[j];
  if (tid == TB - 1) offs[NB] = NPTS;
  __syncthreads();                                   // B4

  // ---- 4. scatter (atomicSub on hist -> reverse fill; offs untouched) ----
  int pos[VPT];
  #pragma unroll
  for (int s = 0; s < VPT; ++s) {
    int b = binof(v[s], mn, inv);
    unsigned old = atomicSub(&hist[b], 1u);
    int p = (int)(offs[b] + old - 1u);
    pos[s] = p | (b << 14);
    xs[phys(p)] = v[s];
  }
  __syncthreads();                                   // B5: hist all-zero (dead)

  // ---- 5. parallel rank within bin -> exact sorted position (stable via slot) ----
  int tgt[VPT];
  #pragma unroll
  for (int s = 0; s < VPT; ++s) {
    int b  = pos[s] >> 14;
    int pp = pos[s] & 0x3FFF;
    int s0 = (int)offs[b];
    int e0 = (int)offs[b + 1];
    float vv = v[s];
    int r = 0;
    for (int j = s0; j < e0; ++j) {
      float xj = xs[phys(j)];
      r += (xj < vv || (xj == vv && j < pp)) ? 1 : 0;
    }
    tgt[s] = s0 + r;
  }
  __syncthreads();                                   // B6; pos[] dead

  // ---- 6. write sorted order from registers ----
  #pragma unroll
  for (int s = 0; s < VPT; ++s) xs[phys(tgt[s])] = v[s];
  __syncthreads();                                   // B7: xs sorted; v[] dead

  // ---- 7. window read + core flags + FS seed + backward seed ----
  const int p0 = tid * VPT;
  float w[VPT + 8];
  #pragma unroll
  for (int k = 0; k < VPT + 8; ++k) {
    int i = p0 - 4 + k;
    w[k] = (i < 0) ? -INFINITY : ((i >= NPTS) ? INFINITY : xs[phys(i)]);
  }
  unsigned int coremask = 0u;
  FS ch = fsid();
  int fi = BIGI; float fv = 0.f;
  #pragma unroll
  for (int s = 0; s < VPT; ++s) {
    float xi = w[s + 4];
    float lo = xi - EPSF, hi = xi + EPSF;
    bool core = false;
    #pragma unroll
    for (int t = 0; t < MINS; ++t)
      core |= (w[s + 4 - t] >= lo) && (w[s + 8 - t] <= hi);
    if (core) {
      coremask |= (1u << s);
      if (!ch.h) { ch.h = 1; ch.f = xi; }
      else if ((xi - ch.l) > EPSF) ++ch.c;
      ch.l = xi;
      if (fi == BIGI) { fi = p0 + s; fv = xi; }
    }
  }

  // ---- 8+9 fused: forward FS scan AND backward next-core scan, one barrier ----
  FS cur = ch;
  for (int d = 1; d < 64; d <<= 1) {
    FS u;
    u.h = __shfl_up(cur.h, d);
    u.f = __shfl_up(cur.f, d);
    u.l = __shfl_up(cur.l, d);
    u.c = __shfl_up(cur.c, d);
    FS cmb = fscomb(u, cur);
    if (lane >= d) cur = cmb;
  }
  FS exs;
  exs.h = __shfl_up(cur.h, 1);
  exs.f = __shfl_up(cur.f, 1);
  exs.l = __shfl_up(cur.l, 1);
  exs.c = __shfl_up(cur.c, 1);
  if (lane == 0) exs = fsid();

  int ri = fi; float rv = fv;
  for (int d = 1; d < 64; d <<= 1) {
    int ui = __shfl_down(ri, d); float uv = __shfl_down(rv, d);
    if (lane < 64 - d && ui < ri) { ri = ui; rv = uv; }
  }
  int Ri = __shfl_down(ri, 1); float Rv = __shfl_down(rv, 1);
  if (lane == 63) Ri = BIGI;

  if (lane == 63) { sh[wid] = cur.h; sf[wid] = cur.f; sl[wid] = cur.l; sc[wid] = cur.c; }
  if (lane == 0)  { wri[wid] = ri;  wrv[wid] = rv; }
  __syncthreads();                                   // B8 (single barrier for both scans)

  FS pre = fsid();
  for (int w2 = 0; w2 < wid; ++w2) {
    FS t; t.h = sh[w2]; t.f = sf[w2]; t.l = sl[w2]; t.c = sc[w2];
    pre = fscomb(pre, t);
  }
  FS sp = fscomb(pre, exs);
  for (int w2 = wid + 1; w2 < 16; ++w2)
    if (wri[w2] < Ri) { Ri = wri[w2]; Rv = wrv[w2]; }

  // ---- 10. single forward label pass (core + border inline) ----
  float P  = sp.h ? sp.l : -INFINITY;       // last core value so far
  int starts = sp.h ? (sp.c + 1) : 0;       // starts-1 = label of P
  #pragma unroll
  for (int s = 0; s < VPT; ++s) {
    int i = p0 + s;
    float xi = w[s + 4];
    short lb;
    if ((coremask >> s) & 1u) {
      if ((xi - P) > EPSF) ++starts;
      P = xi;
      lb = (short)(starts - 1);
    } else {
      float dl = xi - P;                    // +inf when no left core
      unsigned hb = coremask >> (s + 1);    // later cores within this thread
      float Rv2; bool has;
      if (hb) { int j = s + 1 + __builtin_ctz(hb); Rv2 = w[4 + j]; has = true; }
      else    { Rv2 = Rv; has = (Ri < NPTS); }
      float dr = has ? (Rv2 - xi) : INFINITY;
      lb = -1;
      if (fminf(dl, dr) <= EPSF)
        lb = (short)((dl <= dr) ? (starts - 1)
                                : (starts - 1 + (((Rv2 - P) > EPSF) ? 1 : 0)));
    }
    lab[lphys(i)] = lb;
  }
  if (tid == TB - 1) nclg[bd] = starts;
  __syncthreads();                                   // B9: labels visible

  // ---- 11. unsort via tgt; coalesced (b,d,n) label writes ----
  #pragma unroll
  for (int s = 0; s < VPT; ++s)
    labels[(size_t)bd * NPTS + tid + s * TB] = lab[lphys(tgt[s])];
}

// ------- fused zero+scatter with in-block colmap build; vectorized label reads -------
__global__ void __launch_bounds__(TB) kout(const short* __restrict__ labels,
                                           const int* __restrict__ ncl,
                                           float* __restrict__ out) {
  const int tid  = threadIdx.x;
  const int lane = tid & 63;
  const int wid  = tid >> 6;
  const int b    = blockIdx.x >> 5;
  const int n0   = (blockIdx.x & 31) * 512 + wid * 32;

  __shared__ int cmLDS[NCMAX];
  for (int k = tid; k < NCMAX; k += TB) cmLDS[k] = -1;
  __syncthreads();
  if (tid < 64) {
    int vcnt = ncl[b * 64 + tid];
    int incl = vcnt;
    for (int d = 1; d < 64; d <<= 1) {
      int u = __shfl_up(incl, d);
      if (tid >= d) incl += u;
    }
    int off = incl - vcnt;               // exclusive prefix over dims
    for (int k = 0; k < vcnt; ++k) {
      int col = off + k;
      if (col < NCMAX) cmLDS[col] = tid | (k << 8);
    }
  }
  __syncthreads();

  int dk[8], kk[8];
  #pragma unroll
  for (int k = 0; k < 8; ++k) {
    int col = (k < 4) ? (lane * 4 + k) : (256 + lane * 4 + (k - 4));
    int m = cmLDS[col];
    dk[k] = (m >= 0) ? (m & 255) : 0;
    kk[k] = (m >= 0) ? (m >> 8) : 0x7FFF;   // sentinel never matches a label
  }
  const short* lb_b = labels + (size_t)b * NDIM * NPTS;

  #pragma unroll
  for (int rc = 0; rc < 4; ++rc) {
    short8 L[8];
    #pragma unroll
    for (int k = 0; k < 8; ++k)
      L[k] = *(const short8*)(lb_b + (size_t)dk[k] * NPTS + n0 + rc * 8);
    #pragma unroll
    for (int r2 = 0; r2 < 8; ++r2) {
      int n = n0 + rc * 8 + r2;
      float o[8];
      #pragma unroll
      for (int k = 0; k < 8; ++k)
        o[k] = (L[k][r2] == (short)kk[k]) ? 1.0f : 0.0f;
      f32x4* op = (f32x4*)(out + ((size_t)b * NPTS + n) * NCMAX);
      f32x4 lo4 = { o[0], o[1], o[2], o[3] };
      f32x4 hi4 = { o[4], o[5], o[6], o[7] };
      __builtin_nontemporal_store(lo4, &op[lane]);
      __builtin_nontemporal_store(hi4, &op[64 + lane]);
    }
  }
}

extern "C" void kernel_launch(void* const* d_in, const int* in_sizes, int n_in,
                              void* d_out, int out_size, void* d_ws, size_t ws_size,
                              hipStream_t stream) {
  const float* feat = (const float*)d_in[0];
  float* out = (float*)d_out;

  char* ws = (char*)d_ws;
  size_t xt_b   = (size_t)NBATCH * NPTS * NDIM * 4;   // 32 MB
  size_t lbl_b  = (size_t)NBATCH * NPTS * NDIM * 2;   // 16 MB
  float* xt     = (float*)ws;
  short* labels = (short*)(ws + xt_b);
  int*   ncl    = (int*)(ws + xt_b + lbl_b);          // 2 KB

  ktrans  <<<NBATCH * (NPTS / 64), 256, 0, stream>>>(feat, xt);
  kdbscan <<<NBATCH * NDIM, TB, 0, stream>>>(xt, labels, ncl);
  kout    <<<NBATCH * 32, TB, 0, stream>>>(labels, ncl, out);
}

// Round 17
// 148.720 us; speedup vs baseline: 1.0998x; 1.0076x over previous
//
#include <hip/hip_runtime.h>

#define NPTS   16384
#define NDIM   64
#define NBATCH 8
#define TB     1024
#define VPT    16      // NPTS / TB
#define NB     8192    // histogram bins
#define BPT    8       // NB / TB
#define EPSF   0.1f
#define MINS   5
#define NCMAX  512
#define BIGI   0x3fffffff

typedef short short8 __attribute__((ext_vector_type(8)));
typedef float f32x4  __attribute__((ext_vector_type(4)));

// LDS swizzles: spread per-thread-contiguous accesses across banks (bijective XOR)
__device__ __forceinline__ int phys(int i)  { return i ^ ((i >> 5) & 15); }          // float array
__device__ __forceinline__ int lphys(int i) { return i ^ (((i >> 6) & 31) << 1); }   // short array

__device__ __forceinline__ int binof(float x, float mn, float inv) {
  float fb = (x - mn) * inv;
  int b = (int)fb;
  if (fb < 0.f) b = 0;
  if (b > NB - 1) b = NB - 1;
  return b;
}

// ---------------- transpose (B,N,D) -> (B,D,N) ----------------
__global__ void ktrans(const float* __restrict__ f, float* __restrict__ xt) {
  __shared__ float tile[64][65];
  int blk = blockIdx.x;
  int b   = blk >> 8;
  int n0  = (blk & 255) << 6;
  for (int i = threadIdx.x; i < 64 * 64; i += 256) {
    int n = i >> 6, d = i & 63;
    tile[n][d] = f[((size_t)b * NPTS + n0 + n) * NDIM + d];
  }
  __syncthreads();
  for (int i = threadIdx.x; i < 64 * 64; i += 256) {
    int d = i >> 6, n = i & 63;
    xt[((size_t)b * NDIM + d) * NPTS + n0 + n] = tile[n][d];
  }
}

// forward-scan monoid: (has core, first core val, last core val, #internal starts)
struct FS { int h; float f; float l; int c; };
__device__ __forceinline__ FS fsid() { FS r; r.h = 0; r.f = 0.f; r.l = 0.f; r.c = 0; return r; }
__device__ __forceinline__ FS fscomb(FS a, FS b) {
  FS r;
  r.h = a.h | b.h;
  r.f = a.h ? a.f : b.f;
  r.l = b.h ? b.l : a.l;
  int gap = (a.h && b.h && ((b.f - a.l) > EPSF)) ? 1 : 0;
  r.c = a.c + b.c + gap;
  return r;
}

// ---------------- per-(b,d) exact 1-D DBSCAN (8-barrier schedule) ----------------
__global__ void __launch_bounds__(TB) kdbscan(const float* __restrict__ xt,
                                              short* __restrict__ labels,
                                              int* __restrict__ nclg) {
  const int tid  = threadIdx.x;
  const int lane = tid & 63;
  const int wid  = tid >> 6;
  const int bd   = blockIdx.x;
  const float* __restrict__ x = xt + (size_t)bd * NPTS;

  __shared__ float xs[NPTS];            // 64 KB (phys-swizzled)
  __shared__ unsigned int hist[NB];     // 32 KB : counts (kept) -> lab[] alias
  __shared__ unsigned int offs[NB + 1]; // 32 KB : bin STARTS (read-only after phase 3)
  __shared__ float wmn[16], wmx[16];
  __shared__ unsigned int wsum[16];
  __shared__ int   sh[16];  __shared__ float sf[16], sl[16]; __shared__ int sc[16];
  __shared__ int   wri[16]; __shared__ float wrv[16];
  short* lab = (short*)hist;            // lphys-swizzled labels per sorted position

  // ---- 1. hist init overlapped with load + min/max ----
  for (int i = tid; i < NB; i += TB) hist[i] = 0u;
  float v[VPT];
  float mn = INFINITY, mx = -INFINITY;
  #pragma unroll
  for (int s = 0; s < VPT; ++s) {
    v[s] = x[tid + s * TB];
    mn = fminf(mn, v[s]); mx = fmaxf(mx, v[s]);
  }
  for (int d = 1; d < 64; d <<= 1) {
    mn = fminf(mn, __shfl_xor(mn, d));
    mx = fmaxf(mx, __shfl_xor(mx, d));
  }
  if (lane == 0) { wmn[wid] = mn; wmx[wid] = mx; }
  __syncthreads();                                   // B1: hist zeroed + wmn/wmx visible
  mn = wmn[0]; mx = wmx[0];
  for (int w = 1; w < 16; ++w) { mn = fminf(mn, wmn[w]); mx = fmaxf(mx, wmx[w]); }
  float range = mx - mn;
  float inv = (range > 0.f) ? ((float)NB / range) : 0.f;

  // ---- 2. histogram; SAVE returned arrival index as the future slot ----
  int pos[VPT];                                      // r | b<<14
  #pragma unroll
  for (int s = 0; s < VPT; ++s) {
    int b = binof(v[s], mn, inv);
    unsigned r = atomicAdd(&hist[b], 1u);
    pos[s] = (int)r | (b << 14);
  }
  __syncthreads();                                   // B2

  // ---- 3. exclusive prefix sum -> offs = bin starts; offs[NB] = NPTS ----
  unsigned int loc[BPT];
  unsigned int run = 0;
  const int bbase = tid * BPT;
  #pragma unroll
  for (int j = 0; j < BPT; ++j) { loc[j] = run; run += hist[bbase + j]; }
  unsigned int incl = run;
  for (int d = 1; d < 64; d <<= 1) {
    unsigned int u = __shfl_up(incl, d);
    if (lane >= d) incl += u;
  }
  unsigned int exc = __shfl_up(incl, 1);
  if (lane == 0) exc = 0u;
  if (lane == 63) wsum[wid] = incl;
  __syncthreads();                                   // B3
  unsigned int wb = 0;
  for (int w = 0; w < wid; ++w) wb += wsum[w];
  unsigned int tb0 = wb + exc;
  #pragma unroll
  for (int j = 0; j < BPT; ++j) offs[bbase + j] = tb0 + loc[j];
  if (tid == TB - 1) offs[NB] = NPTS;
  __syncthreads();                                   // B4

  // ---- 4. scatter WITHOUT atomics: slot = offs[b] + saved arrival index ----
  #pragma unroll
  for (int s = 0; s < VPT; ++s) {
    int b = pos[s] >> 14;
    int p = (int)offs[b] + (pos[s] & 0x3FFF);
    pos[s] = p | (b << 14);
    xs[phys(p)] = v[s];
  }
  __syncthreads();                                   // B5

  // ---- 5. parallel rank within bin -> exact sorted position (stable via slot) ----
  int tgt[VPT];
  #pragma unroll
  for (int s = 0; s < VPT; ++s) {
    int b  = pos[s] >> 14;
    int pp = pos[s] & 0x3FFF;
    int s0 = (int)offs[b];
    int e0 = (int)offs[b + 1];
    float vv = v[s];
    int r = 0;
    for (int j = s0; j < e0; ++j) {
      float xj = xs[phys(j)];
      r += (xj < vv || (xj == vv && j < pp)) ? 1 : 0;
    }
    tgt[s] = s0 + r;
  }
  __syncthreads();                                   // B6; pos[] dead

  // ---- 6. write sorted order from registers ----
  #pragma unroll
  for (int s = 0; s < VPT; ++s) xs[phys(tgt[s])] = v[s];
  __syncthreads();                                   // B7: xs sorted; v[] dead

  // ---- 7. window: own 16 via LDS, ±4 halo via lane shuffles (LDS only at wave edges) ----
  const int p0 = tid * VPT;
  float w[VPT + 8];
  #pragma unroll
  for (int k = 0; k < VPT; ++k) w[k + 4] = xs[phys(p0 + k)];
  // halo left: previous thread's s=12..15; halo right: next thread's s=0..3
  #pragma unroll
  for (int k = 0; k < 4; ++k) {
    float hl = __shfl_up(w[16 + k], 1);      // p0-4+k for lane>0
    float hr = __shfl_down(w[4 + k], 1);     // p0+16+k for lane<63
    if (lane == 0)  hl = (p0 - 4 + k < 0)      ? -INFINITY : xs[phys(p0 - 4 + k)];
    if (lane == 63) hr = (p0 + 16 + k >= NPTS) ?  INFINITY : xs[phys(p0 + 16 + k)];
    w[k] = hl;
    w[20 + k] = hr;
  }
  unsigned int coremask = 0u;
  FS ch = fsid();
  int fi = BIGI; float fv = 0.f;
  #pragma unroll
  for (int s = 0; s < VPT; ++s) {
    float xi = w[s + 4];
    float lo = xi - EPSF, hi = xi + EPSF;
    bool core = false;
    #pragma unroll
    for (int t = 0; t < MINS; ++t)
      core |= (w[s + 4 - t] >= lo) && (w[s + 8 - t] <= hi);
    if (core) {
      coremask |= (1u << s);
      if (!ch.h) { ch.h = 1; ch.f = xi; }
      else if ((xi - ch.l) > EPSF) ++ch.c;
      ch.l = xi;
      if (fi == BIGI) { fi = p0 + s; fv = xi; }
    }
  }

  // ---- 8+9 fused: forward FS scan AND backward next-core scan, one barrier ----
  FS cur = ch;
  for (int d = 1; d < 64; d <<= 1) {
    FS u;
    u.h = __shfl_up(cur.h, d);
    u.f = __shfl_up(cur.f, d);
    u.l = __shfl_up(cur.l, d);
    u.c = __shfl_up(cur.c, d);
    FS cmb = fscomb(u, cur);
    if (lane >= d) cur = cmb;
  }
  FS exs;
  exs.h = __shfl_up(cur.h, 1);
  exs.f = __shfl_up(cur.f, 1);
  exs.l = __shfl_up(cur.l, 1);
  exs.c = __shfl_up(cur.c, 1);
  if (lane == 0) exs = fsid();

  int ri = fi; float rv = fv;
  for (int d = 1; d < 64; d <<= 1) {
    int ui = __shfl_down(ri, d); float uv = __shfl_down(rv, d);
    if (lane < 64 - d && ui < ri) { ri = ui; rv = uv; }
  }
  int Ri = __shfl_down(ri, 1); float Rv = __shfl_down(rv, 1);
  if (lane == 63) Ri = BIGI;

  if (lane == 63) { sh[wid] = cur.h; sf[wid] = cur.f; sl[wid] = cur.l; sc[wid] = cur.c; }
  if (lane == 0)  { wri[wid] = ri;  wrv[wid] = rv; }
  __syncthreads();                                   // B8 (single barrier for both scans)

  FS pre = fsid();
  for (int w2 = 0; w2 < wid; ++w2) {
    FS t; t.h = sh[w2]; t.f = sf[w2]; t.l = sl[w2]; t.c = sc[w2];
    pre = fscomb(pre, t);
  }
  FS sp = fscomb(pre, exs);
  for (int w2 = wid + 1; w2 < 16; ++w2)
    if (wri[w2] < Ri) { Ri = wri[w2]; Rv = wrv[w2]; }

  // ---- 10. single forward label pass (core + border inline) ----
  float P  = sp.h ? sp.l : -INFINITY;       // last core value so far
  int starts = sp.h ? (sp.c + 1) : 0;       // starts-1 = label of P
  #pragma unroll
  for (int s = 0; s < VPT; ++s) {
    int i = p0 + s;
    float xi = w[s + 4];
    short lb;
    if ((coremask >> s) & 1u) {
      if ((xi - P) > EPSF) ++starts;
      P = xi;
      lb = (short)(starts - 1);
    } else {
      float dl = xi - P;                    // +inf when no left core
      unsigned hb = coremask >> (s + 1);    // later cores within this thread
      float Rv2; bool has;
      if (hb) { int j = s + 1 + __builtin_ctz(hb); Rv2 = w[4 + j]; has = true; }
      else    { Rv2 = Rv; has = (Ri < NPTS); }
      float dr = has ? (Rv2 - xi) : INFINITY;
      lb = -1;
      if (fminf(dl, dr) <= EPSF)
        lb = (short)((dl <= dr) ? (starts - 1)
                                : (starts - 1 + (((Rv2 - P) > EPSF) ? 1 : 0)));
    }
    lab[lphys(i)] = lb;
  }
  if (tid == TB - 1) nclg[bd] = starts;
  __syncthreads();                                   // B9: labels visible

  // ---- 11. unsort via tgt; coalesced (b,d,n) label writes ----
  #pragma unroll
  for (int s = 0; s < VPT; ++s)
    labels[(size_t)bd * NPTS + tid + s * TB] = lab[lphys(tgt[s])];
}

// ------- fused zero+scatter with in-block colmap build; vectorized label reads -------
__global__ void __launch_bounds__(TB) kout(const short* __restrict__ labels,
                                           const int* __restrict__ ncl,
                                           float* __restrict__ out) {
  const int tid  = threadIdx.x;
  const int lane = tid & 63;
  const int wid  = tid >> 6;
  const int b    = blockIdx.x >> 5;
  const int n0   = (blockIdx.x & 31) * 512 + wid * 32;

  __shared__ int cmLDS[NCMAX];
  for (int k = tid; k < NCMAX; k += TB) cmLDS[k] = -1;
  __syncthreads();
  if (tid < 64) {
    int vcnt = ncl[b * 64 + tid];
    int incl = vcnt;
    for (int d = 1; d < 64; d <<= 1) {
      int u = __shfl_up(incl, d);
      if (tid >= d) incl += u;
    }
    int off = incl - vcnt;               // exclusive prefix over dims
    for (int k = 0; k < vcnt; ++k) {
      int col = off + k;
      if (col < NCMAX) cmLDS[col] = tid | (k << 8);
    }
  }
  __syncthreads();

  int dk[8], kk[8];
  #pragma unroll
  for (int k = 0; k < 8; ++k) {
    int col = (k < 4) ? (lane * 4 + k) : (256 + lane * 4 + (k - 4));
    int m = cmLDS[col];
    dk[k] = (m >= 0) ? (m & 255) : 0;
    kk[k] = (m >= 0) ? (m >> 8) : 0x7FFF;   // sentinel never matches a label
  }
  const short* lb_b = labels + (size_t)b * NDIM * NPTS;

  #pragma unroll
  for (int rc = 0; rc < 4; ++rc) {
    short8 L[8];
    #pragma unroll
    for (int k = 0; k < 8; ++k)
      L[k] = *(const short8*)(lb_b + (size_t)dk[k] * NPTS + n0 + rc * 8);
    #pragma unroll
    for (int r2 = 0; r2 < 8; ++r2) {
      int n = n0 + rc * 8 + r2;
      float o[8];
      #pragma unroll
      for (int k = 0; k < 8; ++k)
        o[k] = (L[k][r2] == (short)kk[k]) ? 1.0f : 0.0f;
      f32x4* op = (f32x4*)(out + ((size_t)b * NPTS + n) * NCMAX);
      f32x4 lo4 = { o[0], o[1], o[2], o[3] };
      f32x4 hi4 = { o[4], o[5], o[6], o[7] };
      __builtin_nontemporal_store(lo4, &op[lane]);
      __builtin_nontemporal_store(hi4, &op[64 + lane]);
    }
  }
}

extern "C" void kernel_launch(void* const* d_in, const int* in_sizes, int n_in,
                              void* d_out, int out_size, void* d_ws, size_t ws_size,
                              hipStream_t stream) {
  const float* feat = (const float*)d_in[0];
  float* out = (float*)d_out;

  char* ws = (char*)d_ws;
  size_t xt_b   = (size_t)NBATCH * NPTS * NDIM * 4;   // 32 MB
  size_t lbl_b  = (size_t)NBATCH * NPTS * NDIM * 2;   // 16 MB
  float* xt     = (float*)ws;
  short* labels = (short*)(ws + xt_b);
  int*   ncl    = (int*)(ws + xt_b + lbl_b);          // 2 KB

  ktrans  <<<NBATCH * (NPTS / 64), 256, 0, stream>>>(feat, xt);
  kdbscan <<<NBATCH * NDIM, TB, 0, stream>>>(xt, labels, ncl);
  kout    <<<NBATCH * 32, TB, 0, stream>>>(labels, ncl, out);
}